// Round 19
// baseline (93.244 us; speedup 1.0000x reference)
//
#include <hip/hip_runtime.h>
#include <hip/hip_bf16.h>
#include <hip/hip_fp16.h>
#include <math.h>

#define NHEADS 8
#define CDIM 256
#define NTOK 2304   // 48*48
#define BATCH 4
#define NBH 32      // BATCH*NHEADS
#define NJT 36      // NTOK/64 (j tiles)
#define NNT 36      // n tiles (64-token)
#define NBT 18      // attn block tiles (128-token)
#define NJH 12      // j tiles per third (NJT/3)
#define SCALE 0.17677669529663687f
#define QK_SCALE 0.2550348594934535f  // SCALE * log2(e): logits in exp2 domain

typedef __attribute__((ext_vector_type(8))) short short8;
typedef __attribute__((ext_vector_type(4))) float f32x4;
typedef __attribute__((ext_vector_type(4))) unsigned int uint4v;
typedef __attribute__((ext_vector_type(2))) unsigned int uint2v;

__device__ inline unsigned cvt_pk_bf16(float lo, float hi) {
  unsigned r;
  asm("v_cvt_pk_bf16_f32 %0, %1, %2" : "=v"(r) : "v"(lo), "v"(hi));
  return r;
}
// exp2 via compiler intrinsic: bare v_exp_f32, hazards handled by compiler.
#define EXP2R(x) __builtin_amdgcn_exp2f(x)

// split a,b into bf16 hi words (packed) and bf16 lo-residual words (packed)
__device__ inline void split_hl_pair(float a, float b, unsigned& hh, unsigned& ll) {
  hh = cvt_pk_bf16(a, b);
  const float ha = __uint_as_float(hh << 16);
  const float hb = __uint_as_float(hh & 0xffff0000u);
  ll = cvt_pk_bf16(a - ha, b - hb);
}
__device__ inline void glds16(const char* src, char* ldsbase) {
  __builtin_amdgcn_global_load_lds(
      (const __attribute__((address_space(1))) unsigned int*)src,
      (__attribute__((address_space(3))) unsigned int*)ldsbase, 16, 0, 0);
}

// ---------------------------------------------------------------------------
// prep_w (merged qkv+proj): split W rows into bf16 hi/lo swizzled layout.
// grid (16, 8): otile 0-11 -> whl (scale otile<4 by QK_SCALE), 12-15 -> whlp
// ---------------------------------------------------------------------------
__global__ __launch_bounds__(256) void prep_w(const float* __restrict__ Wq,
                                              const float* __restrict__ Wp,
                                              unsigned short* __restrict__ whl,
                                              unsigned short* __restrict__ whlp) {
  __shared__ float T[64 * 36];
  const int tid = threadIdx.x;
  const int otile = blockIdx.x, kc = blockIdx.y;
  const float* W = (otile < 12) ? Wq : Wp;
  const int ot = (otile < 12) ? otile : otile - 12;
  const float qs = (otile < 4) ? QK_SCALE : 1.f;
#pragma unroll
  for (int p = 0; p < 8; ++p) {
    int idx = p * 256 + tid;
    int c = idx & 31, o = idx >> 5;
    T[o * 36 + c] = W[(size_t)(ot * 64 + o) * CDIM + kc * 32 + c] * qs;
  }
  __syncthreads();
  const int o = tid & 63, coct = tid >> 6;  // 0..3
  uint4v h4, l4;
#pragma unroll
  for (int e = 0; e < 8; e += 2) {
    unsigned hh, ll;
    split_hl_pair(T[o * 36 + coct * 8 + e], T[o * 36 + coct * 8 + e + 1], hh, ll);
    h4[e >> 1] = hh;
    l4[e >> 1] = ll;
  }
  unsigned short* base =
      ((otile < 12) ? whl : whlp) + ((size_t)(ot * 8 + kc)) * 4096 + o * 64;
  *(uint4v*)&base[(coct ^ (o & 7)) << 3] = h4;
  *(uint4v*)&base[((coct + 4) ^ (o & 7)) << 3] = l4;
}

// ---------------------------------------------------------------------------
// prep_x: transpose + split x[b][c][n] -> xhl[b][ntile][kc][64 n][8 slots][8]
// (hi/lo kept — round 14 proven path)
// ---------------------------------------------------------------------------
__global__ __launch_bounds__(256) void prep_x(const float* __restrict__ x,
                                              unsigned short* __restrict__ xhl) {
  __shared__ float T[64 * 36];
  const int tid = threadIdx.x;
  const int ntile = blockIdx.x, kc = blockIdx.y, b = blockIdx.z;
#pragma unroll
  for (int p = 0; p < 8; ++p) {
    int idx = p * 256 + tid;
    int n = idx & 63, c = idx >> 6;
    T[n * 36 + c] = x[((size_t)(b * CDIM + kc * 32 + c)) * NTOK + ntile * 64 + n];
  }
  __syncthreads();
  const int n = tid & 63, coct = tid >> 6;
  uint4v h4, l4;
#pragma unroll
  for (int e = 0; e < 8; e += 2) {
    unsigned hh, ll;
    split_hl_pair(T[n * 36 + coct * 8 + e], T[n * 36 + coct * 8 + e + 1], hh, ll);
    h4[e >> 1] = hh;
    l4[e >> 1] = ll;
  }
  unsigned short* base = xhl + ((size_t)((b * NNT + ntile) * 8 + kc)) * 4096 + n * 64;
  *(uint4v*)&base[(coct ^ (n & 7)) << 3] = h4;
  *(uint4v*)&base[((coct + 4) ^ (n & 7)) << 3] = l4;
}

// ---------------------------------------------------------------------------
// MFMA GEMM, 64x64 tile, K=256, bf16 hi/lo 3-product split, 2-phase pipeline.
// 1-D grid, XCD-cluster swizzle. MODE 0: qkv -> qhl (hi/lo) / khl (HI-ONLY,
// paired-row layout) / vhl. MODE 1: proj -> fp32 out+bias; B staged by FUSED
// 3-WAY COMBINE (sums three fp16 numerator partials + three l partials).
// ---------------------------------------------------------------------------
template <int MODE>
__global__ __launch_bounds__(256) void gemm_mfma(const unsigned short* __restrict__ Ahl,
                                                 const unsigned short* __restrict__ Bhl,
                                                 unsigned short* __restrict__ qhl,
                                                 unsigned short* __restrict__ khl,
                                                 unsigned short* __restrict__ vhl,
                                                 float* __restrict__ outp,
                                                 const float* __restrict__ bias,
                                                 const __half* __restrict__ pnum01,
                                                 const __half* __restrict__ pnum2,
                                                 const float* __restrict__ pl) {
  constexpr int OT = (MODE == 0) ? 12 : 4;
  constexpr int TOT = 36 * 4 * OT;
  __shared__ __align__(128) char smem[32768];
  const int tid = threadIdx.x;
  const int w = tid >> 6, L = tid & 63;
  const int g = L >> 4, li = L & 15, sw = li & 7;
  const int bid = blockIdx.x;
  const int wid = (bid & 7) * (TOT / 8) + (bid >> 3);  // bijective (TOT%8==0)
  const int otile = wid % OT;
  const int cl = wid / OT;
  const int ntile = cl % 36, b = cl / 36;
  const char* Asrc = (const char*)(Ahl + (size_t)otile * 8 * 4096);
  const char* Bsrc = (const char*)(Bhl + (size_t)((b * NNT + ntile) * 8) * 4096);

  f32x4 acc[4];
#pragma unroll
  for (int t = 0; t < 4; ++t) acc[t] = (f32x4){0.f, 0.f, 0.f, 0.f};

  auto stageA = [&](int kc, int p) {
    const char* as = Asrc + (size_t)kc * 8192;
    char* ad = smem + p * 16384;
    glds16(as + w * 2048 + L * 16, ad + w * 2048);
    glds16(as + w * 2048 + 1024 + L * 16, ad + w * 2048 + 1024);
  };
  auto stageB = [&](int kc, int p) {
    const char* bs = Bsrc + (size_t)kc * 8192;
    char* bd = smem + p * 16384 + 8192;
    glds16(bs + w * 2048 + L * 16, bd + w * 2048);
    glds16(bs + w * 2048 + 1024 + L * 16, bd + w * 2048 + 1024);
  };

  // MODE 1 fused-combine B staging state (held in VGPRs across MFMA section)
  uint4v u0, u1, u2;
  float inv_s = 0.f;
  const int cn = tid & 63, coct = tid >> 6;  // thread -> (token, c-octet)
  auto issueB = [&](int kc) {
    const int bh2 = b * 8 + kc;
    const int nt128 = ntile >> 1;
    const int q128 = ((ntile & 1) << 6) | cn;
    const size_t nb = ((size_t)(bh2 * NBT + nt128)) * 4096 + (size_t)q128 * 32 + coct * 8;
    u0 = *(const uint4v*)(pnum01 + nb);
    u1 = *(const uint4v*)(pnum01 + 2359296 + nb);
    u2 = *(const uint4v*)(pnum2 + nb);
    const size_t lrow = ((size_t)bh2 * NBT + nt128) * 128 + q128;
    const size_t lstride = (size_t)NBH * NBT * 128;
    inv_s = 1.f / (pl[lrow] + pl[lstride + lrow] + pl[2 * lstride + lrow]);
  };
  auto writeB = [&](int p) {
    float vals[8];
#pragma unroll
    for (int i = 0; i < 4; ++i) {
      unsigned a = u0[i], bb2 = u1[i], cc2 = u2[i];
      float2 fa = __half22float2(*(__half2*)&a);
      float2 fb = __half22float2(*(__half2*)&bb2);
      float2 fc = __half22float2(*(__half2*)&cc2);
      vals[i * 2] = (fa.x + fb.x + fc.x) * inv_s;
      vals[i * 2 + 1] = (fa.y + fb.y + fc.y) * inv_s;
    }
    uint4v h4, l4;
#pragma unroll
    for (int e = 0; e < 8; e += 2) {
      unsigned hh, ll;
      split_hl_pair(vals[e], vals[e + 1], hh, ll);
      h4[e >> 1] = hh;
      l4[e >> 1] = ll;
    }
    char* bd = smem + p * 16384 + 8192;
    *(uint4v*)(bd + cn * 128 + ((coct ^ (cn & 7)) << 4)) = h4;
    *(uint4v*)(bd + cn * 128 + (((coct + 4) ^ (cn & 7)) << 4)) = l4;
  };

  if constexpr (MODE == 1) {
    issueB(0);
    stageA(0, 0);
    writeB(0);
  } else {
    stageA(0, 0);
    stageB(0, 0);
  }
#pragma unroll 2
  for (int kc = 0; kc < 8; ++kc) {
    __syncthreads();  // stage(kc) visible (vm + lgkm); previous compute done
    if constexpr (MODE == 1) {
      if (kc < 7) {
        issueB(kc + 1);          // loads in flight under this kc's MFMAs
        stageA(kc + 1, (kc + 1) & 1);
      }
    } else {
      if (kc < 7) {
        stageA(kc + 1, (kc + 1) & 1);
        stageB(kc + 1, (kc + 1) & 1);
      }
    }
    const char* ab = smem + (kc & 1) * 16384;
    const char* bb = ab + 8192;
    const char* ar = ab + (w * 16 + li) * 128;
    const short8 ahi = *(const short8*)(ar + ((g ^ sw) << 4));
    const short8 alo = *(const short8*)(ar + (((g + 4) ^ sw) << 4));
    __builtin_amdgcn_s_setprio(1);
#pragma unroll
    for (int t = 0; t < 4; ++t) {
      const char* br = bb + (t * 16 + li) * 128;
      const short8 bhi = *(const short8*)(br + ((g ^ sw) << 4));
      const short8 blo = *(const short8*)(br + (((g + 4) ^ sw) << 4));
      acc[t] = __builtin_amdgcn_mfma_f32_16x16x32_bf16(ahi, bhi, acc[t], 0, 0, 0);
      acc[t] = __builtin_amdgcn_mfma_f32_16x16x32_bf16(alo, bhi, acc[t], 0, 0, 0);
      acc[t] = __builtin_amdgcn_mfma_f32_16x16x32_bf16(ahi, blo, acc[t], 0, 0, 0);
    }
    __builtin_amdgcn_s_setprio(0);
    if constexpr (MODE == 1) {
      if (kc < 7) writeB((kc + 1) & 1);  // combine+split+ds_write after MFMAs
    }
  }

  if constexpr (MODE == 1) {
#pragma unroll
    for (int t = 0; t < 4; ++t)
#pragma unroll
      for (int r = 0; r < 4; ++r) {
        const int o = otile * 64 + w * 16 + g * 4 + r;
        outp[((size_t)(b * CDIM + o)) * NTOK + ntile * 64 + t * 16 + li] =
            acc[t][r] + bias[o];
      }
  } else {
    // bounce through LDS: T[64 n][68 words]
    __syncthreads();
    float* T = (float*)smem;
#pragma unroll
    for (int t = 0; t < 4; ++t)
      *(f32x4*)&T[(t * 16 + li) * 68 + w * 16 + g * 4] = acc[t];
    __syncthreads();
    const int s = otile >> 2;  // 0=q 1=k 2=v
    if (s < 2) {
#pragma unroll
      for (int it = 0; it < 2; ++it) {
        const int n = tid & 63, oct = (tid >> 6) + it * 4;  // 0..7
        const int og = otile * 64 + oct * 8;
        const int h = (og >> 5) & 7;
        const int bh = b * 8 + h;
        const int dc = oct & 3;  // d-chunk within head
        if (s == 0) {
          uint4v h4, l4;
#pragma unroll
          for (int e = 0; e < 8; e += 2) {
            unsigned hh, ll;
            split_hl_pair(T[n * 68 + oct * 8 + e], T[n * 68 + oct * 8 + e + 1], hh, ll);
            h4[e >> 1] = hh;
            l4[e >> 1] = ll;
          }
          const int ng = ntile * 64 + n;
          unsigned short* row = qhl + ((size_t)bh * NTOK + ng) * 64;
          *(uint4v*)&row[(dc ^ (ng & 7)) << 3] = h4;
          *(uint4v*)&row[((dc + 4) ^ (ng & 7)) << 3] = l4;
        } else {
          // K: HI-ONLY, paired-row layout (32 rows x 128B per 64-token tile):
          // token n -> row ((n>>1)&1)*16 + (n>>2), slot ((n&1)*4+dc)^((n>>2)&7)
          uint4v h4;
#pragma unroll
          for (int e = 0; e < 8; e += 2)
            h4[e >> 1] = cvt_pk_bf16(T[n * 68 + oct * 8 + e], T[n * 68 + oct * 8 + e + 1]);
          const int rw = (((n >> 1) & 1) << 4) | (n >> 2);
          const int slot = (((n & 1) << 2) | dc) ^ ((n >> 2) & 7);
          unsigned short* tilep = khl + ((size_t)bh * NTOK + ntile * 64) * 32;
          *(uint4v*)&tilep[rw * 64 + (slot << 3)] = h4;
        }
      }
    } else {
      // v: single bf16, rows = d, cols = j
#pragma unroll
      for (int hh = 0; hh < 2; ++hh) {
        const int d = tid & 31, joct = tid >> 5;  // 0..7
        uint4v v4;
#pragma unroll
        for (int e = 0; e < 8; e += 2)
          v4[e >> 1] = cvt_pk_bf16(T[(joct * 8 + e) * 68 + hh * 32 + d],
                                   T[(joct * 8 + e + 1) * 68 + hh * 32 + d]);
        const int o = otile * 64 + hh * 32 + d;
        const int bh = b * 8 + ((o >> 5) & 7);
        unsigned short* base = vhl + (((size_t)bh * NJT + ntile) * 32 + d) * 64;
        *(uint4v*)&base[(joct ^ (d & 7)) << 3] = v4;
      }
    }
  }
}

// ---------------------------------------------------------------------------
// MFMA flash attention, 8 waves x 16 q-rows, 3-way j-split (z=0..2, 12 tiles
// each). K HI-ONLY paired-row layout (conflict-free, round-18 proven).
// 12 MFMAs/iter, 8 glds/iter, 32KB LDS. grid (18,32,3), block 512.
// ---------------------------------------------------------------------------
__global__ __launch_bounds__(512) void attn_mfma(const unsigned short* __restrict__ qhl,
                                                 const unsigned short* __restrict__ khl,
                                                 const unsigned short* __restrict__ vhl,
                                                 __half* __restrict__ pnum01,
                                                 __half* __restrict__ pnum2,
                                                 float* __restrict__ pl) {
  __shared__ __align__(128) char smem[32768];
  // layout: K dbuf 2x4KB @0 ; V dbuf 2x4KB @8192 ; P 8x2KB @16384
  const int tid = threadIdx.x;
  const int w = tid >> 6, L = tid & 63;
  const int g = L >> 4, li = L & 15, sw = li & 7;
  const int z = blockIdx.z;

  // T1 bijective XCD swizzle (576 % 8 == 0); z slowest -> thirds share XCD
  const int bid = blockIdx.x + NBT * blockIdx.y;               // 0..575
  const int idx = (bid & 7) * ((NBT * NBH) / 8) + (bid >> 3);
  const int ntile = idx % NBT;
  const int bh = idx / NBT;
  const int i0 = ntile * 128 + w * 16;

  const size_t qrow = ((size_t)bh * NTOK + i0 + li) * 64;
  const short8 qhi = *(const short8*)&qhl[qrow + ((g ^ sw) << 3)];
  const short8 qlo = *(const short8*)&qhl[qrow + (((g + 4) ^ sw) << 3)];

  f32x4 o0 = {0.f, 0.f, 0.f, 0.f}, o1 = {0.f, 0.f, 0.f, 0.f};
  float l[4] = {0.f, 0.f, 0.f, 0.f};

  const char* kslab = (const char*)(khl + (size_t)bh * NTOK * 32);
  const char* vslab = (const char*)(vhl + (size_t)bh * NJT * 2048);
  char* pw = smem + 16384 + w * 2048;
  const int jt0 = z * NJH;

  auto stage = [&](int jt, int p) {
    if (w < 4) {  // K tile 4KB: waves 0-3
      const char* ks = kslab + (size_t)jt * 4096;
      glds16(ks + w * 1024 + L * 16, smem + p * 4096 + w * 1024);
    } else {      // V tile 4KB: waves 4-7
      const char* vs = vslab + (size_t)jt * 4096;
      glds16(vs + (w - 4) * 1024 + L * 16, smem + 8192 + p * 4096 + (w - 4) * 1024);
    }
  };

  stage(jt0, 0);
#pragma unroll 2
  for (int t = 0; t < NJH; ++t) {
    __syncthreads();  // stage(t) landed; all waves done with buf t-1
    if (t + 1 < NJH) stage(jt0 + t + 1, (t + 1) & 1);
    const char* Kb = smem + (t & 1) * 4096;
    const char* Vb = smem + 8192 + (t & 1) * 4096;

    // ---- QK^T: 4 j-subtiles, 2-MFMA split (K hi-only, paired rows) ----
    f32x4 sc[4];
    __builtin_amdgcn_s_setprio(1);
#pragma unroll
    for (int u = 0; u < 4; ++u) {
      const char* kr = Kb + (((u >> 1) * 16 + li) << 7);
      const int slot = (((u & 1) << 2) | g) ^ sw;
      const short8 khi = *(const short8*)(kr + (slot << 4));
      f32x4 c = {0.f, 0.f, 0.f, 0.f};
      c = __builtin_amdgcn_mfma_f32_16x16x32_bf16(qhi, khi, c, 0, 0, 0);
      c = __builtin_amdgcn_mfma_f32_16x16x32_bf16(qlo, khi, c, 0, 0, 0);
      sc[u] = c;
    }
    __builtin_amdgcn_s_setprio(0);

    // ---- shift-free softmax: p = 2^sc ----
#pragma unroll
    for (int r = 0; r < 4; ++r) {
      const float p0 = EXP2R(sc[0][r]);
      const float p1 = EXP2R(sc[1][r]);
      const float p2 = EXP2R(sc[2][r]);
      const float p3 = EXP2R(sc[3][r]);
      l[r] += (p0 + p1) + (p2 + p3);
      const int il = g * 4 + r;
      uint2v pk;
      pk.x = cvt_pk_bf16(p0, p1);
      pk.y = cvt_pk_bf16(p2, p3);
      *(uint2v*)(pw + il * 128 +
                 ((((li >> 1) ^ (il & 7)) << 4) | ((li & 1) << 3))) = pk;
    }

    // ---- PV ----
    __builtin_amdgcn_s_setprio(1);
#pragma unroll
    for (int ksb = 0; ksb < 2; ++ksb) {
      const short8 pa = *(const short8*)(pw + li * 128 + (((ksb * 4 + g) ^ sw) << 4));
      const short8 vb0 = *(const short8*)(Vb + li * 128 + (((ksb * 4 + g) ^ sw) << 4));
      const short8 vb1 = *(const short8*)(Vb + (16 + li) * 128 + (((ksb * 4 + g) ^ sw) << 4));
      o0 = __builtin_amdgcn_mfma_f32_16x16x32_bf16(pa, vb0, o0, 0, 0, 0);
      o1 = __builtin_amdgcn_mfma_f32_16x16x32_bf16(pa, vb1, o1, 0, 0, 0);
    }
    __builtin_amdgcn_s_setprio(0);
  }

  // final l reduction across the row's 16 lanes
#pragma unroll
  for (int r = 0; r < 4; ++r) {
#pragma unroll
    for (int off = 1; off < 16; off <<= 1) l[r] += __shfl_xor(l[r], off, 64);
  }

  // ---- epilogue: raw-numerator bounce via LDS, fp16 partial write ----
  __syncthreads();
  float* T = (float*)smem;  // [128 q][36 words] = 18432 B (fits 32KB)
  const size_t lbase = ((size_t)(z * NBH + bh) * NBT + ntile) * 128;
#pragma unroll
  for (int r = 0; r < 4; ++r) {
    const int q = w * 16 + g * 4 + r;
    T[q * 36 + li] = o0[r];
    T[q * 36 + 16 + li] = o1[r];
    if (li == 0) pl[lbase + q] = l[r];
  }
  __syncthreads();
  const int q = tid & 127, coct = tid >> 7;  // coct 0..3
  uint4v u;
#pragma unroll
  for (int e = 0; e < 8; e += 2) {
    __half2 hh = __floats2half2_rn(T[q * 36 + coct * 8 + e],
                                   T[q * 36 + coct * 8 + e + 1]);
    u[e >> 1] = *(unsigned*)&hh;
  }
  __half* pbase = (z == 2) ? pnum2 : (pnum01 + (size_t)z * 2359296);
  __half* pn = pbase + ((size_t)(bh * NBT + ntile)) * 4096 + q * 32 + coct * 8;
  *(uint4v*)pn = u;
}

// ---------------------------------------------------------------------------
extern "C" void kernel_launch(void* const* d_in, const int* in_sizes, int n_in,
                              void* d_out, int out_size, void* d_ws, size_t ws_size,
                              hipStream_t stream) {
  const float* x      = (const float*)d_in[0];
  const float* w_qkv  = (const float*)d_in[1];
  const float* w_proj = (const float*)d_in[2];
  const float* b_proj = (const float*)d_in[3];
  float* out = (float*)d_out;

  unsigned short* qhl = (unsigned short*)d_ws;               // 32*2304*64
  unsigned short* khl = qhl + (size_t)NBH * NTOK * 64;       // 32*2304*32 (hi only)
  unsigned short* vhl = khl + (size_t)NBH * NTOK * 32;       // 32*36*2048
  unsigned short* xhl = vhl + (size_t)NBH * NJT * 2048;      // 4*36*8*4096 (hi/lo)
  unsigned short* whl = xhl + (size_t)BATCH * NNT * 8 * 4096;   // 12*8*4096
  unsigned short* whlp = whl + (size_t)12 * 8 * 4096;           // 4*8*4096
  float* pl = (float*)(whlp + (size_t)4 * 8 * 4096);            // 3*32*18*128 fp32
  __half* pnum2 = (__half*)(pl + (size_t)3 * NBH * NBT * 128);  // 2,359,296 fp16

  // pnum partials 0-1 alias xhl (dead after gemm<0>); partial 2 is fresh ws.
  __half* pnum01 = (__half*)xhl;

  prep_w<<<dim3(16, 8), 256, 0, stream>>>(w_qkv, w_proj, whl, whlp);
  prep_x<<<dim3(NNT, 8, BATCH), 256, 0, stream>>>(x, xhl);

  gemm_mfma<0><<<1728, 256, 0, stream>>>(whl, xhl, qhl, khl, vhl, nullptr, nullptr,
                                         nullptr, nullptr, nullptr);

  attn_mfma<<<dim3(NBT, NBH, 3), 512, 0, stream>>>(qhl, khl, vhl, pnum01, pnum2, pl);

  gemm_mfma<1><<<576, 256, 0, stream>>>(whlp, nullptr, nullptr, nullptr, nullptr,
                                        out, b_proj, pnum01, pnum2, pl);
}

// Round 20
// 83.913 us; speedup vs baseline: 1.1112x; 1.1112x over previous
//
#include <hip/hip_runtime.h>
#include <hip/hip_bf16.h>
#include <hip/hip_fp16.h>
#include <math.h>

#define NHEADS 8
#define CDIM 256
#define NTOK 2304   // 48*48
#define BATCH 4
#define NBH 32      // BATCH*NHEADS
#define NJT 36      // NTOK/64 (j tiles)
#define NNT 36      // n tiles (64-token)
#define NBT 18      // attn block tiles (128-token)
#define NJH 12      // j tiles per third (NJT/3)
#define SCALE 0.17677669529663687f
#define QK_SCALE 0.2550348594934535f  // SCALE * log2(e): logits in exp2 domain

typedef __attribute__((ext_vector_type(8))) short short8;
typedef __attribute__((ext_vector_type(4))) float f32x4;
typedef __attribute__((ext_vector_type(4))) unsigned int uint4v;
typedef __attribute__((ext_vector_type(2))) unsigned int uint2v;

__device__ inline unsigned cvt_pk_bf16(float lo, float hi) {
  unsigned r;
  asm("v_cvt_pk_bf16_f32 %0, %1, %2" : "=v"(r) : "v"(lo), "v"(hi));
  return r;
}
// exp2 via compiler intrinsic: bare v_exp_f32, hazards handled by compiler.
#define EXP2R(x) __builtin_amdgcn_exp2f(x)

// split a,b into bf16 hi words (packed) and bf16 lo-residual words (packed)
__device__ inline void split_hl_pair(float a, float b, unsigned& hh, unsigned& ll) {
  hh = cvt_pk_bf16(a, b);
  const float ha = __uint_as_float(hh << 16);
  const float hb = __uint_as_float(hh & 0xffff0000u);
  ll = cvt_pk_bf16(a - ha, b - hb);
}
__device__ inline void glds16(const char* src, char* ldsbase) {
  __builtin_amdgcn_global_load_lds(
      (const __attribute__((address_space(1))) unsigned int*)src,
      (__attribute__((address_space(3))) unsigned int*)ldsbase, 16, 0, 0);
}

// ---------------------------------------------------------------------------
// prep_w (merged qkv+proj): split W rows into bf16 hi/lo swizzled layout.
// grid (16, 8): otile 0-11 -> whl (scale otile<4 by QK_SCALE), 12-15 -> whlp
// ---------------------------------------------------------------------------
__global__ __launch_bounds__(256) void prep_w(const float* __restrict__ Wq,
                                              const float* __restrict__ Wp,
                                              unsigned short* __restrict__ whl,
                                              unsigned short* __restrict__ whlp) {
  __shared__ float T[64 * 36];
  const int tid = threadIdx.x;
  const int otile = blockIdx.x, kc = blockIdx.y;
  const float* W = (otile < 12) ? Wq : Wp;
  const int ot = (otile < 12) ? otile : otile - 12;
  const float qs = (otile < 4) ? QK_SCALE : 1.f;
#pragma unroll
  for (int p = 0; p < 8; ++p) {
    int idx = p * 256 + tid;
    int c = idx & 31, o = idx >> 5;
    T[o * 36 + c] = W[(size_t)(ot * 64 + o) * CDIM + kc * 32 + c] * qs;
  }
  __syncthreads();
  const int o = tid & 63, coct = tid >> 6;  // 0..3
  uint4v h4, l4;
#pragma unroll
  for (int e = 0; e < 8; e += 2) {
    unsigned hh, ll;
    split_hl_pair(T[o * 36 + coct * 8 + e], T[o * 36 + coct * 8 + e + 1], hh, ll);
    h4[e >> 1] = hh;
    l4[e >> 1] = ll;
  }
  unsigned short* base =
      ((otile < 12) ? whl : whlp) + ((size_t)(ot * 8 + kc)) * 4096 + o * 64;
  *(uint4v*)&base[(coct ^ (o & 7)) << 3] = h4;
  *(uint4v*)&base[((coct + 4) ^ (o & 7)) << 3] = l4;
}

// ---------------------------------------------------------------------------
// prep_x: transpose x -> HI-ONLY bf16, PAIRED-ROW layout (conflict-free):
// xhl[b][ntile][kc] tile = 32 rows x 128B; token n -> row ((n>>5)&1)*16+(n&15),
// chunk c at slot (((n>>4)&1)*4+c)^(n&7).
// ---------------------------------------------------------------------------
__global__ __launch_bounds__(256) void prep_x(const float* __restrict__ x,
                                              unsigned short* __restrict__ xhl) {
  __shared__ float T[64 * 36];
  const int tid = threadIdx.x;
  const int ntile = blockIdx.x, kc = blockIdx.y, b = blockIdx.z;
#pragma unroll
  for (int p = 0; p < 8; ++p) {
    int idx = p * 256 + tid;
    int n = idx & 63, c = idx >> 6;
    T[n * 36 + c] = x[((size_t)(b * CDIM + kc * 32 + c)) * NTOK + ntile * 64 + n];
  }
  __syncthreads();
  const int n = tid & 63, coct = tid >> 6;  // 0..3
  uint4v h4;
#pragma unroll
  for (int e = 0; e < 8; e += 2)
    h4[e >> 1] = cvt_pk_bf16(T[n * 36 + coct * 8 + e], T[n * 36 + coct * 8 + e + 1]);
  const int rw = (((n >> 5) & 1) << 4) | (n & 15);
  const int slot = ((((n >> 4) & 1) << 2) | coct) ^ (n & 7);
  unsigned short* base = xhl + ((size_t)((b * NNT + ntile) * 8 + kc)) * 2048;
  *(uint4v*)&base[rw * 64 + (slot << 3)] = h4;
}

// ---------------------------------------------------------------------------
// MFMA GEMM, 64x64 tile, K=256, 2-MFMA split (ahi*bhi + alo*bhi; B hi-only,
// paired-row conflict-free layout), 2-phase pipeline, XCD-cluster swizzle.
// MODE 0: qkv -> qhl (hi/lo) / khl (hi-only paired-row) / vhl.
// MODE 1: proj -> fp32 out + bias; B staged by FUSED 3-WAY COMBINE (hi-only).
// ---------------------------------------------------------------------------
template <int MODE>
__global__ __launch_bounds__(256) void gemm_mfma(const unsigned short* __restrict__ Ahl,
                                                 const unsigned short* __restrict__ Bhl,
                                                 unsigned short* __restrict__ qhl,
                                                 unsigned short* __restrict__ khl,
                                                 unsigned short* __restrict__ vhl,
                                                 float* __restrict__ outp,
                                                 const float* __restrict__ bias,
                                                 const __half* __restrict__ pnum0,
                                                 const __half* __restrict__ pnum12,
                                                 const float* __restrict__ pl) {
  constexpr int OT = (MODE == 0) ? 12 : 4;
  constexpr int TOT = 36 * 4 * OT;
  __shared__ __align__(128) char smem[24576];  // 2 x (A 8KB + B 4KB)
  const int tid = threadIdx.x;
  const int w = tid >> 6, L = tid & 63;
  const int g = L >> 4, li = L & 15, sw = li & 7;
  const int bid = blockIdx.x;
  const int wid = (bid & 7) * (TOT / 8) + (bid >> 3);  // bijective (TOT%8==0)
  const int otile = wid % OT;
  const int cl = wid / OT;
  const int ntile = cl % 36, b = cl / 36;
  const char* Asrc = (const char*)(Ahl + (size_t)otile * 8 * 4096);
  const char* Bsrc = (const char*)(Bhl + (size_t)((b * NNT + ntile) * 8) * 2048);

  f32x4 acc[4];
#pragma unroll
  for (int t = 0; t < 4; ++t) acc[t] = (f32x4){0.f, 0.f, 0.f, 0.f};

  auto stageA = [&](int kc, int p) {
    const char* as = Asrc + (size_t)kc * 8192;
    char* ad = smem + p * 12288;
    glds16(as + w * 2048 + L * 16, ad + w * 2048);
    glds16(as + w * 2048 + 1024 + L * 16, ad + w * 2048 + 1024);
  };
  auto stageB = [&](int kc, int p) {
    const char* bs = Bsrc + (size_t)kc * 4096;
    char* bd = smem + p * 12288 + 8192;
    glds16(bs + w * 1024 + L * 16, bd + w * 1024);
  };

  // MODE 1 fused-combine B staging state (held in VGPRs across MFMA section)
  uint4v u0, u1, u2;
  float inv_s = 0.f;
  const int cn = tid & 63, coct = tid >> 6;  // thread -> (token, c-octet)
  auto issueB = [&](int kc) {
    const int bh2 = b * 8 + kc;
    const int nt128 = ntile >> 1;
    const int q128 = ((ntile & 1) << 6) | cn;
    const size_t nb = ((size_t)(bh2 * NBT + nt128)) * 4096 + (size_t)q128 * 32 + coct * 8;
    u0 = *(const uint4v*)(pnum0 + nb);
    u1 = *(const uint4v*)(pnum12 + nb);
    u2 = *(const uint4v*)(pnum12 + 2359296 + nb);
    const size_t lrow = ((size_t)bh2 * NBT + nt128) * 128 + q128;
    const size_t lstride = (size_t)NBH * NBT * 128;
    inv_s = 1.f / (pl[lrow] + pl[lstride + lrow] + pl[2 * lstride + lrow]);
  };
  auto writeB = [&](int p) {
    float vals[8];
#pragma unroll
    for (int i = 0; i < 4; ++i) {
      unsigned a = u0[i], bb2 = u1[i], cc2 = u2[i];
      float2 fa = __half22float2(*(__half2*)&a);
      float2 fb = __half22float2(*(__half2*)&bb2);
      float2 fc = __half22float2(*(__half2*)&cc2);
      vals[i * 2] = (fa.x + fb.x + fc.x) * inv_s;
      vals[i * 2 + 1] = (fa.y + fb.y + fc.y) * inv_s;
    }
    uint4v h4;
#pragma unroll
    for (int e = 0; e < 8; e += 2) h4[e >> 1] = cvt_pk_bf16(vals[e], vals[e + 1]);
    const int rw = (((cn >> 5) & 1) << 4) | (cn & 15);
    const int slot = ((((cn >> 4) & 1) << 2) | coct) ^ (cn & 7);
    char* bd = smem + p * 12288 + 8192;
    *(uint4v*)(bd + rw * 128 + (slot << 4)) = h4;
  };

  if constexpr (MODE == 1) {
    issueB(0);
    stageA(0, 0);
    writeB(0);
  } else {
    stageA(0, 0);
    stageB(0, 0);
  }
#pragma unroll 2
  for (int kc = 0; kc < 8; ++kc) {
    __syncthreads();  // stage(kc) visible (vm + lgkm); previous compute done
    if constexpr (MODE == 1) {
      if (kc < 7) {
        issueB(kc + 1);          // loads in flight under this kc's MFMAs
        stageA(kc + 1, (kc + 1) & 1);
      }
    } else {
      if (kc < 7) {
        stageA(kc + 1, (kc + 1) & 1);
        stageB(kc + 1, (kc + 1) & 1);
      }
    }
    const char* ab = smem + (kc & 1) * 12288;
    const char* bb = ab + 8192;
    const char* ar = ab + (w * 16 + li) * 128;
    const short8 ahi = *(const short8*)(ar + ((g ^ sw) << 4));
    const short8 alo = *(const short8*)(ar + (((g + 4) ^ sw) << 4));
    __builtin_amdgcn_s_setprio(1);
#pragma unroll
    for (int t = 0; t < 4; ++t) {
      const char* br = bb + ((((t >> 1) << 4) | li) << 7);
      const short8 bhi = *(const short8*)(br + (((((t & 1) << 2) | g) ^ sw) << 4));
      acc[t] = __builtin_amdgcn_mfma_f32_16x16x32_bf16(ahi, bhi, acc[t], 0, 0, 0);
      acc[t] = __builtin_amdgcn_mfma_f32_16x16x32_bf16(alo, bhi, acc[t], 0, 0, 0);
    }
    __builtin_amdgcn_s_setprio(0);
    if constexpr (MODE == 1) {
      if (kc < 7) writeB((kc + 1) & 1);  // combine+ds_write after MFMAs
    }
  }

  if constexpr (MODE == 1) {
#pragma unroll
    for (int t = 0; t < 4; ++t)
#pragma unroll
      for (int r = 0; r < 4; ++r) {
        const int o = otile * 64 + w * 16 + g * 4 + r;
        outp[((size_t)(b * CDIM + o)) * NTOK + ntile * 64 + t * 16 + li] =
            acc[t][r] + bias[o];
      }
  } else {
    // bounce through LDS: T[64 n][68 words]
    __syncthreads();
    float* T = (float*)smem;
#pragma unroll
    for (int t = 0; t < 4; ++t)
      *(f32x4*)&T[(t * 16 + li) * 68 + w * 16 + g * 4] = acc[t];
    __syncthreads();
    const int s = otile >> 2;  // 0=q 1=k 2=v
    if (s < 2) {
#pragma unroll
      for (int it = 0; it < 2; ++it) {
        const int n = tid & 63, oct = (tid >> 6) + it * 4;  // 0..7
        const int og = otile * 64 + oct * 8;
        const int h = (og >> 5) & 7;
        const int bh = b * 8 + h;
        const int dc = oct & 3;  // d-chunk within head
        if (s == 0) {
          uint4v h4, l4;
#pragma unroll
          for (int e = 0; e < 8; e += 2) {
            unsigned hh, ll;
            split_hl_pair(T[n * 68 + oct * 8 + e], T[n * 68 + oct * 8 + e + 1], hh, ll);
            h4[e >> 1] = hh;
            l4[e >> 1] = ll;
          }
          const int ng = ntile * 64 + n;
          unsigned short* row = qhl + ((size_t)bh * NTOK + ng) * 64;
          *(uint4v*)&row[(dc ^ (ng & 7)) << 3] = h4;
          *(uint4v*)&row[((dc + 4) ^ (ng & 7)) << 3] = l4;
        } else {
          // K: HI-ONLY, paired-row layout (32 rows x 128B per 64-token tile):
          // token n -> row ((n>>1)&1)*16 + (n>>2), slot ((n&1)*4+dc)^((n>>2)&7)
          uint4v h4;
#pragma unroll
          for (int e = 0; e < 8; e += 2)
            h4[e >> 1] = cvt_pk_bf16(T[n * 68 + oct * 8 + e], T[n * 68 + oct * 8 + e + 1]);
          const int rw = (((n >> 1) & 1) << 4) | (n >> 2);
          const int slot = (((n & 1) << 2) | dc) ^ ((n >> 2) & 7);
          unsigned short* tilep = khl + ((size_t)bh * NTOK + ntile * 64) * 32;
          *(uint4v*)&tilep[rw * 64 + (slot << 3)] = h4;
        }
      }
    } else {
      // v: single bf16, rows = d, cols = j
#pragma unroll
      for (int hh = 0; hh < 2; ++hh) {
        const int d = tid & 31, joct = tid >> 5;  // 0..7
        uint4v v4;
#pragma unroll
        for (int e = 0; e < 8; e += 2)
          v4[e >> 1] = cvt_pk_bf16(T[(joct * 8 + e) * 68 + hh * 32 + d],
                                   T[(joct * 8 + e + 1) * 68 + hh * 32 + d]);
        const int o = otile * 64 + hh * 32 + d;
        const int bh = b * 8 + ((o >> 5) & 7);
        unsigned short* base = vhl + (((size_t)bh * NJT + ntile) * 32 + d) * 64;
        *(uint4v*)&base[(joct ^ (d & 7)) << 3] = v4;
      }
    }
  }
}

// ---------------------------------------------------------------------------
// MFMA flash attention, 8 waves x 16 q-rows, 3-way j-split (z=0..2). K is
// HI-ONLY paired-row (conflict-free, round-18/19 proven). 12 MFMAs/iter,
// 8 glds/iter, 32KB LDS. grid (18,32,3), block 512.
// ---------------------------------------------------------------------------
__global__ __launch_bounds__(512) void attn_mfma(const unsigned short* __restrict__ qhl,
                                                 const unsigned short* __restrict__ khl,
                                                 const unsigned short* __restrict__ vhl,
                                                 __half* __restrict__ pnum0,
                                                 __half* __restrict__ pnum12,
                                                 float* __restrict__ pl) {
  __shared__ __align__(128) char smem[32768];
  // layout: K dbuf 2x4KB @0 ; V dbuf 2x4KB @8192 ; P 8x2KB @16384
  const int tid = threadIdx.x;
  const int w = tid >> 6, L = tid & 63;
  const int g = L >> 4, li = L & 15, sw = li & 7;
  const int z = blockIdx.z;

  // T1 bijective XCD swizzle (576 % 8 == 0); z slowest -> thirds share XCD
  const int bid = blockIdx.x + NBT * blockIdx.y;               // 0..575
  const int idx = (bid & 7) * ((NBT * NBH) / 8) + (bid >> 3);
  const int ntile = idx % NBT;
  const int bh = idx / NBT;
  const int i0 = ntile * 128 + w * 16;

  const size_t qrow = ((size_t)bh * NTOK + i0 + li) * 64;
  const short8 qhi = *(const short8*)&qhl[qrow + ((g ^ sw) << 3)];
  const short8 qlo = *(const short8*)&qhl[qrow + (((g + 4) ^ sw) << 3)];

  f32x4 o0 = {0.f, 0.f, 0.f, 0.f}, o1 = {0.f, 0.f, 0.f, 0.f};
  float l[4] = {0.f, 0.f, 0.f, 0.f};

  const char* kslab = (const char*)(khl + (size_t)bh * NTOK * 32);
  const char* vslab = (const char*)(vhl + (size_t)bh * NJT * 2048);
  char* pw = smem + 16384 + w * 2048;
  const int jt0 = z * NJH;

  auto stage = [&](int jt, int p) {
    if (w < 4) {  // K tile 4KB: waves 0-3
      const char* ks = kslab + (size_t)jt * 4096;
      glds16(ks + w * 1024 + L * 16, smem + p * 4096 + w * 1024);
    } else {      // V tile 4KB: waves 4-7
      const char* vs = vslab + (size_t)jt * 4096;
      glds16(vs + (w - 4) * 1024 + L * 16, smem + 8192 + p * 4096 + (w - 4) * 1024);
    }
  };

  stage(jt0, 0);
#pragma unroll 2
  for (int t = 0; t < NJH; ++t) {
    __syncthreads();  // stage(t) landed; all waves done with buf t-1
    if (t + 1 < NJH) stage(jt0 + t + 1, (t + 1) & 1);
    const char* Kb = smem + (t & 1) * 4096;
    const char* Vb = smem + 8192 + (t & 1) * 4096;

    // ---- QK^T: 4 j-subtiles, 2-MFMA split (K hi-only, paired rows) ----
    f32x4 sc[4];
    __builtin_amdgcn_s_setprio(1);
#pragma unroll
    for (int u = 0; u < 4; ++u) {
      const char* kr = Kb + (((u >> 1) * 16 + li) << 7);
      const int slot = (((u & 1) << 2) | g) ^ sw;
      const short8 khi = *(const short8*)(kr + (slot << 4));
      f32x4 c = {0.f, 0.f, 0.f, 0.f};
      c = __builtin_amdgcn_mfma_f32_16x16x32_bf16(qhi, khi, c, 0, 0, 0);
      c = __builtin_amdgcn_mfma_f32_16x16x32_bf16(qlo, khi, c, 0, 0, 0);
      sc[u] = c;
    }
    __builtin_amdgcn_s_setprio(0);

    // ---- shift-free softmax: p = 2^sc ----
#pragma unroll
    for (int r = 0; r < 4; ++r) {
      const float p0 = EXP2R(sc[0][r]);
      const float p1 = EXP2R(sc[1][r]);
      const float p2 = EXP2R(sc[2][r]);
      const float p3 = EXP2R(sc[3][r]);
      l[r] += (p0 + p1) + (p2 + p3);
      const int il = g * 4 + r;
      uint2v pk;
      pk.x = cvt_pk_bf16(p0, p1);
      pk.y = cvt_pk_bf16(p2, p3);
      *(uint2v*)(pw + il * 128 +
                 ((((li >> 1) ^ (il & 7)) << 4) | ((li & 1) << 3))) = pk;
    }

    // ---- PV ----
    __builtin_amdgcn_s_setprio(1);
#pragma unroll
    for (int ksb = 0; ksb < 2; ++ksb) {
      const short8 pa = *(const short8*)(pw + li * 128 + (((ksb * 4 + g) ^ sw) << 4));
      const short8 vb0 = *(const short8*)(Vb + li * 128 + (((ksb * 4 + g) ^ sw) << 4));
      const short8 vb1 = *(const short8*)(Vb + (16 + li) * 128 + (((ksb * 4 + g) ^ sw) << 4));
      o0 = __builtin_amdgcn_mfma_f32_16x16x32_bf16(pa, vb0, o0, 0, 0, 0);
      o1 = __builtin_amdgcn_mfma_f32_16x16x32_bf16(pa, vb1, o1, 0, 0, 0);
    }
    __builtin_amdgcn_s_setprio(0);
  }

  // final l reduction across the row's 16 lanes
#pragma unroll
  for (int r = 0; r < 4; ++r) {
#pragma unroll
    for (int off = 1; off < 16; off <<= 1) l[r] += __shfl_xor(l[r], off, 64);
  }

  // ---- epilogue: raw-numerator bounce via LDS, fp16 partial write ----
  __syncthreads();
  float* T = (float*)smem;  // [128 q][36 words] = 18432 B (fits 32KB)
  const size_t lbase = ((size_t)(z * NBH + bh) * NBT + ntile) * 128;
#pragma unroll
  for (int r = 0; r < 4; ++r) {
    const int q = w * 16 + g * 4 + r;
    T[q * 36 + li] = o0[r];
    T[q * 36 + 16 + li] = o1[r];
    if (li == 0) pl[lbase + q] = l[r];
  }
  __syncthreads();
  const int q = tid & 127, coct = tid >> 7;  // coct 0..3
  uint4v u;
#pragma unroll
  for (int e = 0; e < 8; e += 2) {
    __half2 hh = __floats2half2_rn(T[q * 36 + coct * 8 + e],
                                   T[q * 36 + coct * 8 + e + 1]);
    u[e >> 1] = *(unsigned*)&hh;
  }
  __half* pbase = (z == 0) ? pnum0 : (pnum12 + (size_t)(z - 1) * 2359296);
  __half* pn = pbase + ((size_t)(bh * NBT + ntile)) * 4096 + q * 32 + coct * 8;
  *(uint4v*)pn = u;
}

// ---------------------------------------------------------------------------
extern "C" void kernel_launch(void* const* d_in, const int* in_sizes, int n_in,
                              void* d_out, int out_size, void* d_ws, size_t ws_size,
                              hipStream_t stream) {
  const float* x      = (const float*)d_in[0];
  const float* w_qkv  = (const float*)d_in[1];
  const float* w_proj = (const float*)d_in[2];
  const float* b_proj = (const float*)d_in[3];
  float* out = (float*)d_out;

  unsigned short* qhl = (unsigned short*)d_ws;               // 32*2304*64
  unsigned short* khl = qhl + (size_t)NBH * NTOK * 64;       // 32*2304*32 (hi only)
  unsigned short* vhl = khl + (size_t)NBH * NTOK * 32;       // 32*36*2048
  unsigned short* xhl = vhl + (size_t)NBH * NJT * 2048;      // 4*36*8*2048 (hi only)
  unsigned short* whl = xhl + (size_t)BATCH * NNT * 8 * 2048;   // 12*8*4096
  unsigned short* whlp = whl + (size_t)12 * 8 * 4096;           // 4*8*4096
  float* pl = (float*)(whlp + (size_t)4 * 8 * 4096);            // 3*32*18*128 fp32
  __half* pnum12 = (__half*)(pl + (size_t)3 * NBH * NBT * 128); // 2*2,359,296 fp16

  // pnum partial 0 aliases xhl (2,359,296 halves, dead after gemm<0>);
  // partials 1-2 are fresh ws.
  __half* pnum0 = (__half*)xhl;

  prep_w<<<dim3(16, 8), 256, 0, stream>>>(w_qkv, w_proj, whl, whlp);
  prep_x<<<dim3(NNT, 8, BATCH), 256, 0, stream>>>(x, xhl);

  gemm_mfma<0><<<1728, 256, 0, stream>>>(whl, xhl, qhl, khl, vhl, nullptr, nullptr,
                                         nullptr, nullptr, nullptr);

  attn_mfma<<<dim3(NBT, NBH, 3), 512, 0, stream>>>(qhl, khl, vhl, pnum0, pnum12, pl);

  gemm_mfma<1><<<576, 256, 0, stream>>>(whlp, nullptr, nullptr, nullptr, nullptr,
                                        out, b_proj, pnum0, pnum12, pl);
}

// Round 24
// 80.845 us; speedup vs baseline: 1.1534x; 1.0379x over previous
//
#include <hip/hip_runtime.h>
#include <hip/hip_bf16.h>
#include <hip/hip_fp16.h>
#include <math.h>

#define NHEADS 8
#define CDIM 256
#define NTOK 2304   // 48*48
#define BATCH 4
#define NBH 32      // BATCH*NHEADS
#define NJT 36      // NTOK/64 (j tiles)
#define NNT 36      // n tiles (64-token)
#define NBT 18      // attn block tiles (128-token)
#define NJH 12      // j tiles per third (NJT/3)
#define SCALE 0.17677669529663687f
#define QK_SCALE 0.2550348594934535f  // SCALE * log2(e): logits in exp2 domain

typedef __attribute__((ext_vector_type(8))) short short8;
typedef __attribute__((ext_vector_type(4))) float f32x4;
typedef __attribute__((ext_vector_type(4))) unsigned int uint4v;
typedef __attribute__((ext_vector_type(2))) unsigned int uint2v;

__device__ inline unsigned cvt_pk_bf16(float lo, float hi) {
  unsigned r;
  asm("v_cvt_pk_bf16_f32 %0, %1, %2" : "=v"(r) : "v"(lo), "v"(hi));
  return r;
}
// exp2 via compiler intrinsic: bare v_exp_f32, hazards handled by compiler.
#define EXP2R(x) __builtin_amdgcn_exp2f(x)

// split a,b into bf16 hi words (packed) and bf16 lo-residual words (packed)
__device__ inline void split_hl_pair(float a, float b, unsigned& hh, unsigned& ll) {
  hh = cvt_pk_bf16(a, b);
  const float ha = __uint_as_float(hh << 16);
  const float hb = __uint_as_float(hh & 0xffff0000u);
  ll = cvt_pk_bf16(a - ha, b - hb);
}
__device__ inline void glds16(const char* src, char* ldsbase) {
  __builtin_amdgcn_global_load_lds(
      (const __attribute__((address_space(1))) unsigned int*)src,
      (__attribute__((address_space(3))) unsigned int*)ldsbase, 16, 0, 0);
}

// ---------------------------------------------------------------------------
// prep_wx (merged, structural only): bid 0-127 -> weight hi/lo split;
// bid 128-1279 -> x transpose -> HI-ONLY paired-row layout (conflict-free).
// Bodies bit-identical to round 20's prep_w / prep_x. grid 1280 x 256.
// ---------------------------------------------------------------------------
__global__ __launch_bounds__(256) void prep_wx(const float* __restrict__ Wq,
                                               const float* __restrict__ Wp,
                                               const float* __restrict__ x,
                                               unsigned short* __restrict__ whl,
                                               unsigned short* __restrict__ whlp,
                                               unsigned short* __restrict__ xhl) {
  __shared__ float T[64 * 36];
  const int tid = threadIdx.x;
  const int bid = blockIdx.x;
  if (bid < 128) {
    const int otile = bid & 15, kc = bid >> 4;
    const float* W = (otile < 12) ? Wq : Wp;
    const int ot = (otile < 12) ? otile : otile - 12;
    const float qs = (otile < 4) ? QK_SCALE : 1.f;
#pragma unroll
    for (int p = 0; p < 8; ++p) {
      int idx = p * 256 + tid;
      int c = idx & 31, o = idx >> 5;
      T[o * 36 + c] = W[(size_t)(ot * 64 + o) * CDIM + kc * 32 + c] * qs;
    }
    __syncthreads();
    const int o = tid & 63, coct = tid >> 6;  // 0..3
    uint4v h4, l4;
#pragma unroll
    for (int e = 0; e < 8; e += 2) {
      unsigned hh, ll;
      split_hl_pair(T[o * 36 + coct * 8 + e], T[o * 36 + coct * 8 + e + 1], hh, ll);
      h4[e >> 1] = hh;
      l4[e >> 1] = ll;
    }
    unsigned short* base =
        ((otile < 12) ? whl : whlp) + ((size_t)(ot * 8 + kc)) * 4096 + o * 64;
    *(uint4v*)&base[(coct ^ (o & 7)) << 3] = h4;
    *(uint4v*)&base[((coct + 4) ^ (o & 7)) << 3] = l4;
  } else {
    const int idx = bid - 128;
    const int ntile = idx % 36, kc = (idx / 36) & 7, b = idx / 288;
#pragma unroll
    for (int p = 0; p < 8; ++p) {
      int id2 = p * 256 + tid;
      int n = id2 & 63, c = id2 >> 6;
      T[n * 36 + c] = x[((size_t)(b * CDIM + kc * 32 + c)) * NTOK + ntile * 64 + n];
    }
    __syncthreads();
    const int n = tid & 63, coct = tid >> 6;  // 0..3
    uint4v h4;
#pragma unroll
    for (int e = 0; e < 8; e += 2)
      h4[e >> 1] = cvt_pk_bf16(T[n * 36 + coct * 8 + e], T[n * 36 + coct * 8 + e + 1]);
    const int rw = (((n >> 5) & 1) << 4) | (n & 15);
    const int slot = ((((n >> 4) & 1) << 2) | coct) ^ (n & 7);
    unsigned short* base = xhl + ((size_t)((b * NNT + ntile) * 8 + kc)) * 2048;
    *(uint4v*)&base[rw * 64 + (slot << 3)] = h4;
  }
}

// ---------------------------------------------------------------------------
// MFMA GEMM, 64x64 tile, K=256, 2-MFMA split (ahi*bhi + alo*bhi; B hi-only,
// paired-row conflict-free layout), 2-phase pipeline, XCD-cluster swizzle.
// MODE 0: qkv -> qhl (hi/lo) / khl (hi-only paired-row) / vhl.
// MODE 1: proj -> fp32 out + bias; B staged by FUSED 3-WAY COMBINE (hi-only).
// ---------------------------------------------------------------------------
template <int MODE>
__global__ __launch_bounds__(256) void gemm_mfma(const unsigned short* __restrict__ Ahl,
                                                 const unsigned short* __restrict__ Bhl,
                                                 unsigned short* __restrict__ qhl,
                                                 unsigned short* __restrict__ khl,
                                                 unsigned short* __restrict__ vhl,
                                                 float* __restrict__ outp,
                                                 const float* __restrict__ bias,
                                                 const __half* __restrict__ pnum0,
                                                 const __half* __restrict__ pnum12,
                                                 const float* __restrict__ pl) {
  constexpr int OT = (MODE == 0) ? 12 : 4;
  constexpr int TOT = 36 * 4 * OT;
  __shared__ __align__(128) char smem[24576];  // 2 x (A 8KB + B 4KB)
  const int tid = threadIdx.x;
  const int w = tid >> 6, L = tid & 63;
  const int g = L >> 4, li = L & 15, sw = li & 7;
  const int bid = blockIdx.x;
  const int wid = (bid & 7) * (TOT / 8) + (bid >> 3);  // bijective (TOT%8==0)
  const int otile = wid % OT;
  const int cl = wid / OT;
  const int ntile = cl % 36, b = cl / 36;
  const char* Asrc = (const char*)(Ahl + (size_t)otile * 8 * 4096);
  const char* Bsrc = (const char*)(Bhl + (size_t)((b * NNT + ntile) * 8) * 2048);

  f32x4 acc[4];
#pragma unroll
  for (int t = 0; t < 4; ++t) acc[t] = (f32x4){0.f, 0.f, 0.f, 0.f};

  auto stageA = [&](int kc, int p) {
    const char* as = Asrc + (size_t)kc * 8192;
    char* ad = smem + p * 12288;
    glds16(as + w * 2048 + L * 16, ad + w * 2048);
    glds16(as + w * 2048 + 1024 + L * 16, ad + w * 2048 + 1024);
  };
  auto stageB = [&](int kc, int p) {
    const char* bs = Bsrc + (size_t)kc * 4096;
    char* bd = smem + p * 12288 + 8192;
    glds16(bs + w * 1024 + L * 16, bd + w * 1024);
  };

  // MODE 1 fused-combine B staging state (held in VGPRs across MFMA section)
  uint4v u0, u1, u2;
  float inv_s = 0.f;
  const int cn = tid & 63, coct = tid >> 6;  // thread -> (token, c-octet)
  auto issueB = [&](int kc) {
    const int bh2 = b * 8 + kc;
    const int nt128 = ntile >> 1;
    const int q128 = ((ntile & 1) << 6) | cn;
    const size_t nb = ((size_t)(bh2 * NBT + nt128)) * 4096 + (size_t)q128 * 32 + coct * 8;
    u0 = *(const uint4v*)(pnum0 + nb);
    u1 = *(const uint4v*)(pnum12 + nb);
    u2 = *(const uint4v*)(pnum12 + 2359296 + nb);
    const size_t lrow = ((size_t)bh2 * NBT + nt128) * 128 + q128;
    const size_t lstride = (size_t)NBH * NBT * 128;
    inv_s = 1.f / (pl[lrow] + pl[lstride + lrow] + pl[2 * lstride + lrow]);
  };
  auto writeB = [&](int p) {
    float vals[8];
#pragma unroll
    for (int i = 0; i < 4; ++i) {
      unsigned a = u0[i], bb2 = u1[i], cc2 = u2[i];
      float2 fa = __half22float2(*(__half2*)&a);
      float2 fb = __half22float2(*(__half2*)&bb2);
      float2 fc = __half22float2(*(__half2*)&cc2);
      vals[i * 2] = (fa.x + fb.x + fc.x) * inv_s;
      vals[i * 2 + 1] = (fa.y + fb.y + fc.y) * inv_s;
    }
    uint4v h4;
#pragma unroll
    for (int e = 0; e < 8; e += 2) h4[e >> 1] = cvt_pk_bf16(vals[e], vals[e + 1]);
    const int rw = (((cn >> 5) & 1) << 4) | (cn & 15);
    const int slot = ((((cn >> 4) & 1) << 2) | coct) ^ (cn & 7);
    char* bd = smem + p * 12288 + 8192;
    *(uint4v*)(bd + rw * 128 + (slot << 4)) = h4;
  };

  if constexpr (MODE == 1) {
    issueB(0);
    stageA(0, 0);
    writeB(0);
  } else {
    stageA(0, 0);
    stageB(0, 0);
  }
#pragma unroll 2
  for (int kc = 0; kc < 8; ++kc) {
    __syncthreads();  // stage(kc) visible (vm + lgkm); previous compute done
    if constexpr (MODE == 1) {
      if (kc < 7) {
        issueB(kc + 1);          // loads in flight under this kc's MFMAs
        stageA(kc + 1, (kc + 1) & 1);
      }
    } else {
      if (kc < 7) {
        stageA(kc + 1, (kc + 1) & 1);
        stageB(kc + 1, (kc + 1) & 1);
      }
    }
    const char* ab = smem + (kc & 1) * 12288;
    const char* bb = ab + 8192;
    const char* ar = ab + (w * 16 + li) * 128;
    const short8 ahi = *(const short8*)(ar + ((g ^ sw) << 4));
    const short8 alo = *(const short8*)(ar + (((g + 4) ^ sw) << 4));
    __builtin_amdgcn_s_setprio(1);
#pragma unroll
    for (int t = 0; t < 4; ++t) {
      const char* br = bb + ((((t >> 1) << 4) | li) << 7);
      const short8 bhi = *(const short8*)(br + (((((t & 1) << 2) | g) ^ sw) << 4));
      acc[t] = __builtin_amdgcn_mfma_f32_16x16x32_bf16(ahi, bhi, acc[t], 0, 0, 0);
      acc[t] = __builtin_amdgcn_mfma_f32_16x16x32_bf16(alo, bhi, acc[t], 0, 0, 0);
    }
    __builtin_amdgcn_s_setprio(0);
    if constexpr (MODE == 1) {
      if (kc < 7) writeB((kc + 1) & 1);  // combine+ds_write after MFMAs
    }
  }

  if constexpr (MODE == 1) {
#pragma unroll
    for (int t = 0; t < 4; ++t)
#pragma unroll
      for (int r = 0; r < 4; ++r) {
        const int o = otile * 64 + w * 16 + g * 4 + r;
        outp[((size_t)(b * CDIM + o)) * NTOK + ntile * 64 + t * 16 + li] =
            acc[t][r] + bias[o];
      }
  } else {
    // bounce through LDS: T[64 n][68 words]
    __syncthreads();
    float* T = (float*)smem;
#pragma unroll
    for (int t = 0; t < 4; ++t)
      *(f32x4*)&T[(t * 16 + li) * 68 + w * 16 + g * 4] = acc[t];
    __syncthreads();
    const int s = otile >> 2;  // 0=q 1=k 2=v
    if (s < 2) {
#pragma unroll
      for (int it = 0; it < 2; ++it) {
        const int n = tid & 63, oct = (tid >> 6) + it * 4;  // 0..7
        const int og = otile * 64 + oct * 8;
        const int h = (og >> 5) & 7;
        const int bh = b * 8 + h;
        const int dc = oct & 3;  // d-chunk within head
        if (s == 0) {
          uint4v h4, l4;
#pragma unroll
          for (int e = 0; e < 8; e += 2) {
            unsigned hh, ll;
            split_hl_pair(T[n * 68 + oct * 8 + e], T[n * 68 + oct * 8 + e + 1], hh, ll);
            h4[e >> 1] = hh;
            l4[e >> 1] = ll;
          }
          const int ng = ntile * 64 + n;
          unsigned short* row = qhl + ((size_t)bh * NTOK + ng) * 64;
          *(uint4v*)&row[(dc ^ (ng & 7)) << 3] = h4;
          *(uint4v*)&row[((dc + 4) ^ (ng & 7)) << 3] = l4;
        } else {
          // K: HI-ONLY, paired-row layout (32 rows x 128B per 64-token tile):
          // token n -> row ((n>>1)&1)*16 + (n>>2), slot ((n&1)*4+dc)^((n>>2)&7)
          uint4v h4;
#pragma unroll
          for (int e = 0; e < 8; e += 2)
            h4[e >> 1] = cvt_pk_bf16(T[n * 68 + oct * 8 + e], T[n * 68 + oct * 8 + e + 1]);
          const int rw = (((n >> 1) & 1) << 4) | (n >> 2);
          const int slot = (((n & 1) << 2) | dc) ^ ((n >> 2) & 7);
          unsigned short* tilep = khl + ((size_t)bh * NTOK + ntile * 64) * 32;
          *(uint4v*)&tilep[rw * 64 + (slot << 3)] = h4;
        }
      }
    } else {
      // v: single bf16, rows = d, cols = j
#pragma unroll
      for (int hh = 0; hh < 2; ++hh) {
        const int d = tid & 31, joct = tid >> 5;  // 0..7
        uint4v v4;
#pragma unroll
        for (int e = 0; e < 8; e += 2)
          v4[e >> 1] = cvt_pk_bf16(T[(joct * 8 + e) * 68 + hh * 32 + d],
                                   T[(joct * 8 + e + 1) * 68 + hh * 32 + d]);
        const int o = otile * 64 + hh * 32 + d;
        const int bh = b * 8 + ((o >> 5) & 7);
        unsigned short* base = vhl + (((size_t)bh * NJT + ntile) * 32 + d) * 64;
        *(uint4v*)&base[(joct ^ (d & 7)) << 3] = v4;
      }
    }
  }
}

// ---------------------------------------------------------------------------
// MFMA flash attention, 8 waves x 16 q-rows, 3-way j-split (z=0..2). Q hi/lo
// (2-MFMA QK^T: exact q*khi); K hi-only paired-row (conflict-free).
// 12 MFMAs/iter, 8 glds/iter, 32KB LDS. grid (18,32,3), block 512.
// ---------------------------------------------------------------------------
__global__ __launch_bounds__(512) void attn_mfma(const unsigned short* __restrict__ qhl,
                                                 const unsigned short* __restrict__ khl,
                                                 const unsigned short* __restrict__ vhl,
                                                 __half* __restrict__ pnum0,
                                                 __half* __restrict__ pnum12,
                                                 float* __restrict__ pl) {
  __shared__ __align__(128) char smem[32768];
  // layout: K dbuf 2x4KB @0 ; V dbuf 2x4KB @8192 ; P 8x2KB @16384
  const int tid = threadIdx.x;
  const int w = tid >> 6, L = tid & 63;
  const int g = L >> 4, li = L & 15, sw = li & 7;
  const int z = blockIdx.z;

  // T1 bijective XCD swizzle (576 % 8 == 0); z slowest -> thirds share XCD
  const int bid = blockIdx.x + NBT * blockIdx.y;               // 0..575
  const int idx = (bid & 7) * ((NBT * NBH) / 8) + (bid >> 3);
  const int ntile = idx % NBT;
  const int bh = idx / NBT;
  const int i0 = ntile * 128 + w * 16;

  const size_t qrow = ((size_t)bh * NTOK + i0 + li) * 64;
  const short8 qhi = *(const short8*)&qhl[qrow + ((g ^ sw) << 3)];
  const short8 qlo = *(const short8*)&qhl[qrow + (((g + 4) ^ sw) << 3)];

  f32x4 o0 = {0.f, 0.f, 0.f, 0.f}, o1 = {0.f, 0.f, 0.f, 0.f};
  float l[4] = {0.f, 0.f, 0.f, 0.f};

  const char* kslab = (const char*)(khl + (size_t)bh * NTOK * 32);
  const char* vslab = (const char*)(vhl + (size_t)bh * NJT * 2048);
  char* pw = smem + 16384 + w * 2048;
  const int jt0 = z * NJH;

  auto stage = [&](int jt, int p) {
    if (w < 4) {  // K tile 4KB: waves 0-3
      const char* ks = kslab + (size_t)jt * 4096;
      glds16(ks + w * 1024 + L * 16, smem + p * 4096 + w * 1024);
    } else {      // V tile 4KB: waves 4-7
      const char* vs = vslab + (size_t)jt * 4096;
      glds16(vs + (w - 4) * 1024 + L * 16, smem + 8192 + p * 4096 + (w - 4) * 1024);
    }
  };

  stage(jt0, 0);
#pragma unroll 2
  for (int t = 0; t < NJH; ++t) {
    __syncthreads();  // stage(t) landed; all waves done with buf t-1
    if (t + 1 < NJH) stage(jt0 + t + 1, (t + 1) & 1);
    const char* Kb = smem + (t & 1) * 4096;
    const char* Vb = smem + 8192 + (t & 1) * 4096;

    // ---- QK^T: 4 j-subtiles, 2-MFMA split (K hi-only, paired rows) ----
    f32x4 sc[4];
    __builtin_amdgcn_s_setprio(1);
#pragma unroll
    for (int u = 0; u < 4; ++u) {
      const char* kr = Kb + (((u >> 1) * 16 + li) << 7);
      const int slot = (((u & 1) << 2) | g) ^ sw;
      const short8 khi = *(const short8*)(kr + (slot << 4));
      f32x4 c = {0.f, 0.f, 0.f, 0.f};
      c = __builtin_amdgcn_mfma_f32_16x16x32_bf16(qhi, khi, c, 0, 0, 0);
      c = __builtin_amdgcn_mfma_f32_16x16x32_bf16(qlo, khi, c, 0, 0, 0);
      sc[u] = c;
    }
    __builtin_amdgcn_s_setprio(0);

    // ---- shift-free softmax: p = 2^sc ----
#pragma unroll
    for (int r = 0; r < 4; ++r) {
      const float p0 = EXP2R(sc[0][r]);
      const float p1 = EXP2R(sc[1][r]);
      const float p2 = EXP2R(sc[2][r]);
      const float p3 = EXP2R(sc[3][r]);
      l[r] += (p0 + p1) + (p2 + p3);
      const int il = g * 4 + r;
      uint2v pk;
      pk.x = cvt_pk_bf16(p0, p1);
      pk.y = cvt_pk_bf16(p2, p3);
      *(uint2v*)(pw + il * 128 +
                 ((((li >> 1) ^ (il & 7)) << 4) | ((li & 1) << 3))) = pk;
    }

    // ---- PV ----
    __builtin_amdgcn_s_setprio(1);
#pragma unroll
    for (int ksb = 0; ksb < 2; ++ksb) {
      const short8 pa = *(const short8*)(pw + li * 128 + (((ksb * 4 + g) ^ sw) << 4));
      const short8 vb0 = *(const short8*)(Vb + li * 128 + (((ksb * 4 + g) ^ sw) << 4));
      const short8 vb1 = *(const short8*)(Vb + (16 + li) * 128 + (((ksb * 4 + g) ^ sw) << 4));
      o0 = __builtin_amdgcn_mfma_f32_16x16x32_bf16(pa, vb0, o0, 0, 0, 0);
      o1 = __builtin_amdgcn_mfma_f32_16x16x32_bf16(pa, vb1, o1, 0, 0, 0);
    }
    __builtin_amdgcn_s_setprio(0);
  }

  // final l reduction across the row's 16 lanes
#pragma unroll
  for (int r = 0; r < 4; ++r) {
#pragma unroll
    for (int off = 1; off < 16; off <<= 1) l[r] += __shfl_xor(l[r], off, 64);
  }

  // ---- epilogue: raw-numerator bounce via LDS, fp16 partial write ----
  __syncthreads();
  float* T = (float*)smem;  // [128 q][36 words] = 18432 B (fits 32KB)
  const size_t lbase = ((size_t)(z * NBH + bh) * NBT + ntile) * 128;
#pragma unroll
  for (int r = 0; r < 4; ++r) {
    const int q = w * 16 + g * 4 + r;
    T[q * 36 + li] = o0[r];
    T[q * 36 + 16 + li] = o1[r];
    if (li == 0) pl[lbase + q] = l[r];
  }
  __syncthreads();
  const int q = tid & 127, coct = tid >> 7;  // coct 0..3
  uint4v u;
#pragma unroll
  for (int e = 0; e < 8; e += 2) {
    __half2 hh = __floats2half2_rn(T[q * 36 + coct * 8 + e],
                                   T[q * 36 + coct * 8 + e + 1]);
    u[e >> 1] = *(unsigned*)&hh;
  }
  __half* pbase = (z == 0) ? pnum0 : (pnum12 + (size_t)(z - 1) * 2359296);
  __half* pn = pbase + ((size_t)(bh * NBT + ntile)) * 4096 + q * 32 + coct * 8;
  *(uint4v*)pn = u;
}

// ---------------------------------------------------------------------------
extern "C" void kernel_launch(void* const* d_in, const int* in_sizes, int n_in,
                              void* d_out, int out_size, void* d_ws, size_t ws_size,
                              hipStream_t stream) {
  const float* x      = (const float*)d_in[0];
  const float* w_qkv  = (const float*)d_in[1];
  const float* w_proj = (const float*)d_in[2];
  const float* b_proj = (const float*)d_in[3];
  float* out = (float*)d_out;

  unsigned short* qhl = (unsigned short*)d_ws;               // 32*2304*64 (hi/lo)
  unsigned short* khl = qhl + (size_t)NBH * NTOK * 64;       // 32*2304*32 (hi only)
  unsigned short* vhl = khl + (size_t)NBH * NTOK * 32;       // 32*36*2048
  unsigned short* xhl = vhl + (size_t)NBH * NJT * 2048;      // 4*36*8*2048 (hi only)
  unsigned short* whl = xhl + (size_t)BATCH * NNT * 8 * 2048;   // 12*8*4096
  unsigned short* whlp = whl + (size_t)12 * 8 * 4096;           // 4*8*4096
  float* pl = (float*)(whlp + (size_t)4 * 8 * 4096);            // 3*32*18*128 fp32
  __half* pnum12 = (__half*)(pl + (size_t)3 * NBH * NBT * 128); // 2*2,359,296 fp16

  // pnum partial 0 aliases xhl (2,359,296 halves, dead after gemm<0>);
  // partials 1-2 are fresh ws.
  __half* pnum0 = (__half*)xhl;

  prep_wx<<<1280, 256, 0, stream>>>(w_qkv, w_proj, x, whl, whlp, xhl);

  gemm_mfma<0><<<1728, 256, 0, stream>>>(whl, xhl, qhl, khl, vhl, nullptr, nullptr,
                                         nullptr, nullptr, nullptr);

  attn_mfma<<<dim3(NBT, NBH, 3), 512, 0, stream>>>(qhl, khl, vhl, pnum0, pnum12, pl);

  gemm_mfma<1><<<576, 256, 0, stream>>>(whlp, nullptr, nullptr, nullptr, nullptr,
                                        out, b_proj, pnum0, pnum12, pl);
}